// Round 19
// baseline (283.481 us; speedup 1.0000x reference)
//
#include <hip/hip_runtime.h>
#include <stdint.h>

typedef unsigned short u16;
typedef short bf16x8 __attribute__((ext_vector_type(8)));
typedef float f32x4 __attribute__((ext_vector_type(4)));
typedef float f32x16 __attribute__((ext_vector_type(16)));

#define MFMA16(a, b, c) __builtin_amdgcn_mfma_f32_16x16x32_bf16(a, b, c, 0, 0, 0)
#define MFMA32(a, b, c) __builtin_amdgcn_mfma_f32_32x32x16_bf16(a, b, c, 0, 0, 0)

// async global->LDS, 16B per lane. LDS dest must be linear (base + lane*16).
__device__ __forceinline__ void ld_lds16(const void* g, void* l) {
  __builtin_amdgcn_global_load_lds(
      (const __attribute__((address_space(1))) void*)(uint64_t)(uintptr_t)g,
      (__attribute__((address_space(3))) void*)(uint32_t)(uintptr_t)l,
      16, 0, 0);
}

__device__ __forceinline__ u16 f32_to_bf16(float f) {
  uint32_t u = __float_as_uint(f);
  return (u16)((u + 0x7FFFu + ((u >> 16) & 1u)) >> 16);
}

__device__ __forceinline__ uint32_t cvt_pk_bf16(float a, float b) {
  uint32_t r;
  asm("v_cvt_pk_bf16_f32 %0, %1, %2" : "=v"(r) : "v"(a), "v"(b));
  return r;
}

// v_permlane32_swap_b32: x' = {x.lo32lanes, y.lo32lanes}, y' = {x.hi, y.hi}
__device__ __forceinline__ void perm_swap(uint32_t& x, uint32_t& y) {
  asm volatile("v_permlane32_swap_b32 %0, %1" : "+v"(x), "+v"(y));
}

// ---------------- fused f32 -> bf16 convert (all 6 arrays, one launch) -------
__global__ void cvt_all(const float* __restrict__ xq, const float* __restrict__ xkv,
                        const float* __restrict__ Wq, const float* __restrict__ Wk,
                        const float* __restrict__ Wv, const float* __restrict__ Wo,
                        u16* __restrict__ xq_b, u16* __restrict__ xkv_b,
                        u16* __restrict__ wq_b, u16* __restrict__ wk_b,
                        u16* __restrict__ wv_b, u16* __restrict__ wo_b) {
  const int M4 = 1 << 20;  // 1M float4 = 4M floats
  const int total = 7 * M4 + (M4 >> 1);
  int i = blockIdx.x * blockDim.x + threadIdx.x;
  int stride = gridDim.x * blockDim.x;
  for (; i < total; i += stride) {
    const float* src;
    u16* dst;
    int off;
    if (i < M4)                         { src = xq;  dst = xq_b;  off = i; }
    else if (i < 5 * M4)                { src = xkv; dst = xkv_b; off = i - M4; }
    else if (i < 6 * M4)                { src = Wq;  dst = wq_b;  off = i - 5 * M4; }
    else if (i < 6 * M4 + (M4 >> 2))    { src = Wk;  dst = wk_b;  off = i - 6 * M4; }
    else if (i < 6 * M4 + (M4 >> 1))    { src = Wv;  dst = wv_b;  off = i - 6 * M4 - (M4 >> 2); }
    else                                { src = Wo;  dst = wo_b;  off = i - 6 * M4 - (M4 >> 1); }
    float4 v = reinterpret_cast<const float4*>(src)[off];
    ushort4 o;
    o.x = f32_to_bf16(v.x); o.y = f32_to_bf16(v.y);
    o.z = f32_to_bf16(v.z); o.w = f32_to_bf16(v.w);
    reinterpret_cast<ushort4*>(dst)[off] = o;
  }
}

// ---------------- NT GEMM body, BN=64 (R9-proven; used by gemm_out) ---------
__device__ __forceinline__ void gemm_body(const u16* __restrict__ A,
                                          const u16* __restrict__ B,
                                          void* __restrict__ Cv, int M, int N,
                                          int K, float alpha, int bx, int by,
                                          int outf32, u16* lA, u16* lB) {
  const int tid = threadIdx.x;
  const int lane = tid & 63;
  const int w = tid >> 6;
  const int c = lane & 15, g = lane >> 4;
  const int wm = (w & 1) * 64, wn = (w >> 1) * 32;
  const int m0 = by * 128, n0 = bx * 64;
  const int sr = tid >> 3, sc = tid & 7;

  f32x4 acc[4][2] = {};

  for (int k0 = 0; k0 < K; k0 += 64) {
    __syncthreads();
#pragma unroll
    for (int p = 0; p < 4; ++p) {
      int row = p * 32 + sr;
      int gc = sc ^ (row & 7);
      ld_lds16(A + (size_t)(m0 + row) * K + k0 + gc * 8, &lA[row * 64 + sc * 8]);
    }
#pragma unroll
    for (int p = 0; p < 2; ++p) {
      int idx = p * 256 + tid;
      int row = idx >> 3, cc = idx & 7;
      int gc = cc ^ (row & 7);
      ld_lds16(B + (size_t)(n0 + row) * K + k0 + gc * 8, &lB[row * 64 + cc * 8]);
    }
    __syncthreads();
#pragma unroll
    for (int kc = 0; kc < 2; ++kc) {
      bf16x8 a[4], b[2];
#pragma unroll
      for (int t = 0; t < 4; ++t) {
        int row = wm + t * 16 + c;
        int ch = (g + 4 * kc) ^ (row & 7);
        a[t] = *(const bf16x8*)&lA[row * 64 + ch * 8];
      }
#pragma unroll
      for (int t = 0; t < 2; ++t) {
        int row = wn + t * 16 + c;
        int ch = (g + 4 * kc) ^ (row & 7);
        b[t] = *(const bf16x8*)&lB[row * 64 + ch * 8];
      }
#pragma unroll
      for (int i = 0; i < 4; ++i)
#pragma unroll
        for (int j = 0; j < 2; ++j)
          acc[i][j] = MFMA16(a[i], b[j], acc[i][j]);
    }
  }

#pragma unroll
  for (int i = 0; i < 4; ++i)
#pragma unroll
    for (int j = 0; j < 2; ++j)
#pragma unroll
      for (int r = 0; r < 4; ++r) {
        int mm = m0 + wm + i * 16 + g * 4 + r;
        int nn = n0 + wn + j * 16 + c;
        float v = acc[i][j][r] * alpha;
        if (outf32)
          ((float*)Cv)[(size_t)mm * N + nn] = v;
        else
          ((u16*)Cv)[(size_t)mm * N + nn] = f32_to_bf16(v);
      }
}

// ---------------- NT GEMM body, 128x128 tile (R18-verified, for gemm3) ------
// 16 MFMA per 8 ds_read_b128 per wave per kc-half -- 2x math/LDS-byte of
// BN=64. Needs ~135 VGPR: launch bounds (256,2) (cap at (256,4) spilled, R11).
__device__ __forceinline__ void gemm_body128(const u16* __restrict__ A,
                                             const u16* __restrict__ B,
                                             u16* __restrict__ C, int N, int K,
                                             float alpha, int bx, int by,
                                             u16* lA, u16* lB) {
  const int tid = threadIdx.x;
  const int lane = tid & 63;
  const int w = tid >> 6;
  const int c = lane & 15, g = lane >> 4;
  const int wm = (w & 1) * 64, wn = (w >> 1) * 64;
  const int m0 = by * 128, n0 = bx * 128;
  const int sr = tid >> 3, sc = tid & 7;

  f32x4 acc[4][4] = {};

  for (int k0 = 0; k0 < K; k0 += 64) {
    __syncthreads();
#pragma unroll
    for (int p = 0; p < 4; ++p) {
      int row = p * 32 + sr;
      int gc = sc ^ (row & 7);
      ld_lds16(A + (size_t)(m0 + row) * K + k0 + gc * 8, &lA[row * 64 + sc * 8]);
    }
#pragma unroll
    for (int p = 0; p < 4; ++p) {
      int row = p * 32 + sr;
      int gc = sc ^ (row & 7);
      ld_lds16(B + (size_t)(n0 + row) * K + k0 + gc * 8, &lB[row * 64 + sc * 8]);
    }
    __syncthreads();
#pragma unroll
    for (int kc = 0; kc < 2; ++kc) {
      bf16x8 a[4], b[4];
#pragma unroll
      for (int t = 0; t < 4; ++t) {
        int row = wm + t * 16 + c;
        int ch = (g + 4 * kc) ^ (row & 7);
        a[t] = *(const bf16x8*)&lA[row * 64 + ch * 8];
      }
#pragma unroll
      for (int t = 0; t < 4; ++t) {
        int row = wn + t * 16 + c;
        int ch = (g + 4 * kc) ^ (row & 7);
        b[t] = *(const bf16x8*)&lB[row * 64 + ch * 8];
      }
#pragma unroll
      for (int i = 0; i < 4; ++i)
#pragma unroll
        for (int j = 0; j < 4; ++j)
          acc[i][j] = MFMA16(a[i], b[j], acc[i][j]);
    }
  }

#pragma unroll
  for (int i = 0; i < 4; ++i)
#pragma unroll
    for (int j = 0; j < 4; ++j)
#pragma unroll
      for (int r = 0; r < 4; ++r) {
        int mm = m0 + wm + i * 16 + g * 4 + r;
        int nn = n0 + wn + j * 16 + c;
        C[(size_t)mm * N + nn] = f32_to_bf16(acc[i][j][r] * alpha);
      }
}

// fused launch: 3 input GEMMs, 128x128 tiles, grid 768 = 3 blocks/CU (R18)
__global__ __launch_bounds__(256, 2)
void gemm3(const u16* __restrict__ xq_b, const u16* __restrict__ wq_b,
           u16* __restrict__ Qb, const u16* __restrict__ xkv_b,
           const u16* __restrict__ wk_b, u16* __restrict__ Kb,
           const u16* __restrict__ wv_b, u16* __restrict__ VTb, float qscale) {
  __shared__ u16 lA[128 * 64];
  __shared__ u16 lB[128 * 64];
  int b = blockIdx.x;
  if (b < 256) {
    gemm_body128(xq_b, wq_b, Qb, 2048, 2048, qscale, b & 15, b >> 4, lA, lB);
  } else if (b < 512) {
    b -= 256;
    gemm_body128(xkv_b, wk_b, Kb, 512, 2048, 1.0f, b & 3, b >> 2, lA, lB);
  } else {
    b -= 512;
    gemm_body128(wv_b, xkv_b, VTb, 8192, 2048, 1.0f, b & 63, b >> 6, lA, lB);
  }
}

// single NT GEMM (final output, f32), BN=64 R9 config (grid 32x16 = 2/CU)
__global__ __launch_bounds__(256, 4)
void gemm_out(const u16* __restrict__ A, const u16* __restrict__ B,
              float* __restrict__ Cv) {
  __shared__ u16 lA[128 * 64];
  __shared__ u16 lB[64 * 64];
  gemm_body(A, B, Cv, 2048, 2048, 2048, 1.0f, blockIdx.x, blockIdx.y, 1, lA, lB);
}

// ---------------- fused flash attention v19 ---------------------------------
// R13 structure + QK chain split: each S half accumulates in TWO independent
// MFMA chains (s0a/s0b alternate kc) summed once per tile -- MFMA32 result
// latency no longer serializes 8-deep (pipe occupancy 32cy/SIMD, m119-derived;
// chain latency was the QK critical path). +32 VGPR, no spill at (256,2).
// grid 512 = 2 kvs x 16 qb x 16 h; 4 waves x 32 q-rows; 2 blocks/CU.
__global__ __launch_bounds__(256, 2)
void attn_kernel(const u16* __restrict__ Q, const u16* __restrict__ Kg,
                 const u16* __restrict__ VT, float* __restrict__ Opart,
                 float* __restrict__ mlp) {
  __shared__ u16 lK[2][64 * 128];  // [j][d], chunk^=(j&15) swizzle
  __shared__ u16 lV[2][128 * 64];  // [d][j], chunk^=(d&7) swizzle

  const int tid = threadIdx.x;
  const int w = tid >> 6, lane = tid & 63;
  const int ql = lane & 31, hi = lane >> 5;
  const int bx = blockIdx.x;
  const int h = bx & 15, kvs = bx >> 8;
  const int qbr = (bx >> 4) & 15;
  const int qb = kvs ? qbr : 15 - qbr;  // load-balance remap (R7)
  const int hk = h >> 2;  // GQA
  const int i0 = qb * 128;
  const int q0 = i0 + w * 32;  // wave's 32 q-rows

  const int nt = ((i0 + 6271) >> 6) + 1;
  const int nth = nt >> 1;
  const int t0 = kvs ? nth : 0;
  const int ntt = (kvs ? nt : nth) - t0;
  const int tsafe = (i0 + 6081) >> 6;
  int nmain = tsafe + 1 - t0;
  if (nmain > ntt) nmain = ntt;
  if (nmain < 0) nmain = 0;

  // Q B-frag (32x32x16): lane holds Q[q0+ql][d = kc*16 + hi*8 .. +7]
  bf16x8 qf[8];
#pragma unroll
  for (int kc = 0; kc < 8; ++kc)
    qf[kc] = *(const bf16x8*)&Q[(size_t)(q0 + ql) * 2048 + h * 128 + kc * 16 + hi * 8];

  // ones B-frag for row-sum MFMA (l = P * 1)
  bf16x8 onesB;
#pragma unroll
  for (int i = 0; i < 8; ++i) onesB[i] = (short)0x3F80;

  f32x16 a[4] = {};   // O[q][d]: C-frag row q=(r&3)+8(r>>2)+4hi, col d=dt*32+ql
  f32x16 lacc = {};   // l[q] in C-frag rows (all cols identical)

  auto stage = [&](int buf, int t) {
    const int j0 = t << 6;
#pragma unroll
    for (int p = 0; p < 4; ++p) {
      int idx = p * 256 + tid;
      int row = idx >> 4, cc = idx & 15;
      int gc = cc ^ (row & 15);
      ld_lds16(Kg + (size_t)(j0 + row) * 512 + hk * 128 + gc * 8,
               &lK[buf][row * 128 + cc * 8]);
    }
#pragma unroll
    for (int p = 0; p < 4; ++p) {
      int idx = p * 256 + tid;
      int row = idx >> 3, cc = idx & 7;
      int gc = cc ^ (row & 7);
      ld_lds16(VT + (size_t)(hk * 128 + row) * 8192 + j0 + gc * 8,
               &lV[buf][row * 64 + cc * 8]);
    }
  };

  // finish one S half: exp2 in place, pack to two PV A-frags
  auto finish = [&](f32x16& sv, bf16x8& pA, bf16x8& pB) {
#pragma unroll
    for (int r = 0; r < 16; ++r) sv[r] = __builtin_amdgcn_exp2f(sv[r]);
    uint32_t A0 = cvt_pk_bf16(sv[0], sv[1]);
    uint32_t B0 = cvt_pk_bf16(sv[4], sv[5]);
    perm_swap(A0, B0);
    uint32_t A1 = cvt_pk_bf16(sv[2], sv[3]);
    uint32_t B1 = cvt_pk_bf16(sv[6], sv[7]);
    perm_swap(A1, B1);
    uint32_t A2 = cvt_pk_bf16(sv[8], sv[9]);
    uint32_t B2 = cvt_pk_bf16(sv[12], sv[13]);
    perm_swap(A2, B2);
    uint32_t A3 = cvt_pk_bf16(sv[10], sv[11]);
    uint32_t B3 = cvt_pk_bf16(sv[14], sv[15]);
    perm_swap(A3, B3);
    union { uint32_t u[4]; bf16x8 v; } pa, pb;
    pa.u[0] = A0; pa.u[1] = A1; pa.u[2] = B0; pa.u[3] = B1;
    pb.u[0] = A2; pb.u[1] = A3; pb.u[2] = B2; pb.u[3] = B3;
    pA = pa.v;
    pB = pb.v;
  };

  stage(0, t0);

  int it = 0;
  auto run_tiles = [&](int end, bool domask) {
    for (; it < end; ++it) {
      const int curb = it & 1;
      const int j0 = (t0 + it) << 6;
      if (it + 1 < ntt) {
        stage(curb ^ 1, t0 + it + 1);
        asm volatile("s_waitcnt vmcnt(8)" ::: "memory");
      } else {
        asm volatile("s_waitcnt vmcnt(0)" ::: "memory");
      }
      __builtin_amdgcn_s_barrier();

      bf16x8 pbf[4];
      // phase 1: QK s0 -- TWO independent chains (even/odd kc)
      f32x16 s0a = {}, s0b = {};
      __builtin_amdgcn_s_setprio(1);
#pragma unroll
      for (int kc = 0; kc < 8; kc += 2) {
        int ch0 = kc * 2 + hi;
        int ch1 = (kc + 1) * 2 + hi;
        bf16x8 kf0 = *(const bf16x8*)&lK[curb][ql * 128 + (ch0 ^ (ql & 15)) * 8];
        bf16x8 kf1 = *(const bf16x8*)&lK[curb][ql * 128 + (ch1 ^ (ql & 15)) * 8];
        s0a = MFMA32(kf0, qf[kc], s0a);
        s0b = MFMA32(kf1, qf[kc + 1], s0b);
      }
      __builtin_amdgcn_s_setprio(0);
      // phase 2: QK s1 (two chains, MFMA) || sum+mask+exp+pack s0 (VALU)
      f32x16 s1a = {}, s1b = {};
#pragma unroll
      for (int kc = 0; kc < 8; kc += 2) {
        int ch0 = kc * 2 + hi;
        int ch1 = (kc + 1) * 2 + hi;
        bf16x8 kf0 = *(const bf16x8*)&lK[curb][(32 + ql) * 128 + (ch0 ^ (ql & 15)) * 8];
        bf16x8 kf1 = *(const bf16x8*)&lK[curb][(32 + ql) * 128 + (ch1 ^ (ql & 15)) * 8];
        s1a = MFMA32(kf0, qf[kc], s1a);
        s1b = MFMA32(kf1, qf[kc + 1], s1b);
      }
      s0a += s0b;  // collapse chains (16 v_add_f32, overlaps QK s1)
      if (domask) {
#pragma unroll
        for (int r = 0; r < 16; ++r) {
          int jrow = (r & 3) + 8 * (r >> 2) + 4 * hi;
          if (j0 + jrow > q0 + ql + 6144) s0a[r] = -1e30f;
        }
      }
      finish(s0a, pbf[0], pbf[1]);
      // phase 3: PV s0 + ones (MFMA) || sum+mask+exp+pack s1 (VALU)
      lacc = MFMA32(pbf[0], onesB, lacc);
      lacc = MFMA32(pbf[1], onesB, lacc);
#pragma unroll
      for (int kc = 0; kc < 2; ++kc)
#pragma unroll
        for (int dt = 0; dt < 4; ++dt) {
          int row = dt * 32 + ql;
          int ch = (kc * 2 + hi) ^ (row & 7);
          bf16x8 vf = *(const bf16x8*)&lV[curb][row * 64 + ch * 8];
          a[dt] = MFMA32(pbf[kc], vf, a[dt]);
        }
      s1a += s1b;
      if (domask) {
#pragma unroll
        for (int r = 0; r < 16; ++r) {
          int jrow = (r & 3) + 8 * (r >> 2) + 4 * hi;
          if (j0 + 32 + jrow > q0 + ql + 6144) s1a[r] = -1e30f;
        }
      }
      finish(s1a, pbf[2], pbf[3]);
      // phase 4: PV s1 + ones (pure MFMA cluster)
      __builtin_amdgcn_s_setprio(1);
      lacc = MFMA32(pbf[2], onesB, lacc);
      lacc = MFMA32(pbf[3], onesB, lacc);
#pragma unroll
      for (int kc = 2; kc < 4; ++kc)
#pragma unroll
        for (int dt = 0; dt < 4; ++dt) {
          int row = dt * 32 + ql;
          int ch = (kc * 2 + hi) ^ (row & 7);
          bf16x8 vf = *(const bf16x8*)&lV[curb][row * 64 + ch * 8];
          a[dt] = MFMA32(pbf[kc], vf, a[dt]);
        }
      __builtin_amdgcn_s_setprio(0);

      __builtin_amdgcn_s_barrier();
    }
  };

  run_tiles(nmain, false);  // hot loop: branch-free
  run_tiles(ntt, true);     // tail (<=3 tiles): exact per-lane mask

  // epilogue: store unnormalized partials (f32, [q][d] layout) + l
  const size_t pbase = ((size_t)(kvs * 16 + h) * 16 + qb);
  float* Op = Opart + pbase * 16384;
  float* mlb = mlp + pbase * 256;
#pragma unroll
  for (int dt = 0; dt < 4; ++dt)
#pragma unroll
    for (int r = 0; r < 16; ++r) {
      int qrow = w * 32 + (r & 3) + 8 * (r >> 2) + 4 * hi;
      Op[(size_t)qrow * 128 + dt * 32 + ql] = a[dt][r];
    }
  if (ql == 0) {  // lanes 0 and 32: disjoint q-row sets via hi
#pragma unroll
    for (int r = 0; r < 16; ++r)
      mlb[128 + w * 32 + (r & 3) + 8 * (r >> 2) + 4 * hi] = lacc[r];
  }
}

// ---------------- merge the two KV-half partials (no max: weights = 1) ------
__global__ __launch_bounds__(256)
void attn_merge(const float* __restrict__ Opart, const float* __restrict__ mlp,
                u16* __restrict__ O) {
  const int bx = blockIdx.x;  // h*16 + qb
  const int h = bx >> 4, qb = bx & 15;
  const int q = threadIdx.x & 127, hf = threadIdx.x >> 7;
  const size_t p0 = ((size_t)(0 + h) * 16 + qb);
  const size_t p1 = ((size_t)(16 + h) * 16 + qb);
  float ll0 = mlp[p0 * 256 + 128 + q], ll1 = mlp[p1 * 256 + 128 + q];
  float inv = 1.f / (ll0 + ll1);
  const float* A = Opart + p0 * 16384 + (size_t)q * 128 + hf * 64;
  const float* B = Opart + p1 * 16384 + (size_t)q * 128 + hf * 64;
  u16* out = O + (size_t)(qb * 128 + q) * 2048 + h * 128 + hf * 64;
#pragma unroll
  for (int d = 0; d < 64; d += 4) {
    float4 a = *(const float4*)&A[d];
    float4 b = *(const float4*)&B[d];
    ushort4 o;
    o.x = f32_to_bf16((a.x + b.x) * inv);
    o.y = f32_to_bf16((a.y + b.y) * inv);
    o.z = f32_to_bf16((a.z + b.z) * inv);
    o.w = f32_to_bf16((a.w + b.w) * inv);
    *(ushort4*)&out[d] = o;
  }
}

// ---------------- launch ----------------
extern "C" void kernel_launch(void* const* d_in, const int* in_sizes, int n_in,
                              void* d_out, int out_size, void* d_ws, size_t ws_size,
                              hipStream_t stream) {
  (void)in_sizes; (void)n_in; (void)out_size; (void)ws_size;
  const float* xq = (const float*)d_in[0];   // [2048][2048]
  const float* xkv = (const float*)d_in[1];  // [8192][2048]
  const float* Wq = (const float*)d_in[2];   // [2048][2048]
  const float* Wk = (const float*)d_in[3];   // [512][2048]
  const float* Wv = (const float*)d_in[4];   // [512][2048]
  const float* Wo = (const float*)d_in[5];   // [2048][2048]

  u16* ws = (u16*)d_ws;
  const size_t M1 = 1024 * 1024;
  u16* xq_b  = ws;             // dead after gemm3
  u16* xkv_b = ws + 4 * M1;    // dead after gemm3
  u16* wq_b  = ws + 20 * M1;
  u16* wk_b  = ws + 24 * M1;
  u16* wv_b  = ws + 25 * M1;
  u16* wo_b  = ws + 26 * M1;   // LIVE until gemm_out
  u16* Qb    = ws + 30 * M1;   // pre-scaled by log2e/sqrt(D)
  u16* Kb    = ws + 34 * M1;   // [8192][512]
  u16* VTb   = ws + 38 * M1;   // [512][8192]
  u16* Ob    = ws + 42 * M1;
  // attn partials alias the dead xq_b/xkv_b region (34.1MB <= 40MB)
  float* Opart = (float*)d_ws;            // 2*16*16*128*128 f32
  float* mlptr = Opart + 8388608;         // 2*16*16*256 f32

  cvt_all<<<2048, 256, 0, stream>>>(xq, xkv, Wq, Wk, Wv, Wo,
                                    xq_b, xkv_b, wq_b, wk_b, wv_b, wo_b);

  // Q = x_q Wq^T (scaled); K = x_kv Wk^T; V^T = Wv x_kv^T -- one fused launch
  gemm3<<<768, 256, 0, stream>>>(xq_b, wq_b, Qb, xkv_b, wk_b, Kb, wv_b, VTb,
                                 0.12752837f);

  attn_kernel<<<512, 256, 0, stream>>>(Qb, Kb, VTb, Opart, mlptr);
  attn_merge<<<256, 256, 0, stream>>>(Opart, mlptr, Ob);

  // out = O Wo^T (f32 output)
  gemm_out<<<dim3(32, 16), 256, 0, stream>>>(Ob, wo_b, (float*)d_out);
}

// Round 20
// 264.853 us; speedup vs baseline: 1.0703x; 1.0703x over previous
//
#include <hip/hip_runtime.h>
#include <stdint.h>

typedef unsigned short u16;
typedef short bf16x8 __attribute__((ext_vector_type(8)));
typedef float f32x4 __attribute__((ext_vector_type(4)));
typedef float f32x16 __attribute__((ext_vector_type(16)));

#define MFMA16(a, b, c) __builtin_amdgcn_mfma_f32_16x16x32_bf16(a, b, c, 0, 0, 0)
#define MFMA32(a, b, c) __builtin_amdgcn_mfma_f32_32x32x16_bf16(a, b, c, 0, 0, 0)

// async global->LDS, 16B per lane. LDS dest must be linear (base + lane*16).
__device__ __forceinline__ void ld_lds16(const void* g, void* l) {
  __builtin_amdgcn_global_load_lds(
      (const __attribute__((address_space(1))) void*)(uint64_t)(uintptr_t)g,
      (__attribute__((address_space(3))) void*)(uint32_t)(uintptr_t)l,
      16, 0, 0);
}

__device__ __forceinline__ u16 f32_to_bf16(float f) {
  uint32_t u = __float_as_uint(f);
  return (u16)((u + 0x7FFFu + ((u >> 16) & 1u)) >> 16);
}

__device__ __forceinline__ uint32_t cvt_pk_bf16(float a, float b) {
  uint32_t r;
  asm("v_cvt_pk_bf16_f32 %0, %1, %2" : "=v"(r) : "v"(a), "v"(b));
  return r;
}

// v_permlane32_swap_b32: x' = {x.lo32lanes, y.lo32lanes}, y' = {x.hi, y.hi}
__device__ __forceinline__ void perm_swap(uint32_t& x, uint32_t& y) {
  asm volatile("v_permlane32_swap_b32 %0, %1" : "+v"(x), "+v"(y));
}

// ---------------- fused f32 -> bf16 convert (all 6 arrays, one launch) -------
__global__ void cvt_all(const float* __restrict__ xq, const float* __restrict__ xkv,
                        const float* __restrict__ Wq, const float* __restrict__ Wk,
                        const float* __restrict__ Wv, const float* __restrict__ Wo,
                        u16* __restrict__ xq_b, u16* __restrict__ xkv_b,
                        u16* __restrict__ wq_b, u16* __restrict__ wk_b,
                        u16* __restrict__ wv_b, u16* __restrict__ wo_b) {
  const int M4 = 1 << 20;  // 1M float4 = 4M floats
  const int total = 7 * M4 + (M4 >> 1);
  int i = blockIdx.x * blockDim.x + threadIdx.x;
  int stride = gridDim.x * blockDim.x;
  for (; i < total; i += stride) {
    const float* src;
    u16* dst;
    int off;
    if (i < M4)                         { src = xq;  dst = xq_b;  off = i; }
    else if (i < 5 * M4)                { src = xkv; dst = xkv_b; off = i - M4; }
    else if (i < 6 * M4)                { src = Wq;  dst = wq_b;  off = i - 5 * M4; }
    else if (i < 6 * M4 + (M4 >> 2))    { src = Wk;  dst = wk_b;  off = i - 6 * M4; }
    else if (i < 6 * M4 + (M4 >> 1))    { src = Wv;  dst = wv_b;  off = i - 6 * M4 - (M4 >> 2); }
    else                                { src = Wo;  dst = wo_b;  off = i - 6 * M4 - (M4 >> 1); }
    float4 v = reinterpret_cast<const float4*>(src)[off];
    ushort4 o;
    o.x = f32_to_bf16(v.x); o.y = f32_to_bf16(v.y);
    o.z = f32_to_bf16(v.z); o.w = f32_to_bf16(v.w);
    reinterpret_cast<ushort4*>(dst)[off] = o;
  }
}

// ---------------- NT GEMM body, BN=64 (R9-proven; used by gemm_out) ---------
__device__ __forceinline__ void gemm_body(const u16* __restrict__ A,
                                          const u16* __restrict__ B,
                                          void* __restrict__ Cv, int M, int N,
                                          int K, float alpha, int bx, int by,
                                          int outf32, u16* lA, u16* lB) {
  const int tid = threadIdx.x;
  const int lane = tid & 63;
  const int w = tid >> 6;
  const int c = lane & 15, g = lane >> 4;
  const int wm = (w & 1) * 64, wn = (w >> 1) * 32;
  const int m0 = by * 128, n0 = bx * 64;
  const int sr = tid >> 3, sc = tid & 7;

  f32x4 acc[4][2] = {};

  for (int k0 = 0; k0 < K; k0 += 64) {
    __syncthreads();
#pragma unroll
    for (int p = 0; p < 4; ++p) {
      int row = p * 32 + sr;
      int gc = sc ^ (row & 7);
      ld_lds16(A + (size_t)(m0 + row) * K + k0 + gc * 8, &lA[row * 64 + sc * 8]);
    }
#pragma unroll
    for (int p = 0; p < 2; ++p) {
      int idx = p * 256 + tid;
      int row = idx >> 3, cc = idx & 7;
      int gc = cc ^ (row & 7);
      ld_lds16(B + (size_t)(n0 + row) * K + k0 + gc * 8, &lB[row * 64 + cc * 8]);
    }
    __syncthreads();
#pragma unroll
    for (int kc = 0; kc < 2; ++kc) {
      bf16x8 a[4], b[2];
#pragma unroll
      for (int t = 0; t < 4; ++t) {
        int row = wm + t * 16 + c;
        int ch = (g + 4 * kc) ^ (row & 7);
        a[t] = *(const bf16x8*)&lA[row * 64 + ch * 8];
      }
#pragma unroll
      for (int t = 0; t < 2; ++t) {
        int row = wn + t * 16 + c;
        int ch = (g + 4 * kc) ^ (row & 7);
        b[t] = *(const bf16x8*)&lB[row * 64 + ch * 8];
      }
#pragma unroll
      for (int i = 0; i < 4; ++i)
#pragma unroll
        for (int j = 0; j < 2; ++j)
          acc[i][j] = MFMA16(a[i], b[j], acc[i][j]);
    }
  }

#pragma unroll
  for (int i = 0; i < 4; ++i)
#pragma unroll
    for (int j = 0; j < 2; ++j)
#pragma unroll
      for (int r = 0; r < 4; ++r) {
        int mm = m0 + wm + i * 16 + g * 4 + r;
        int nn = n0 + wn + j * 16 + c;
        float v = acc[i][j][r] * alpha;
        if (outf32)
          ((float*)Cv)[(size_t)mm * N + nn] = v;
        else
          ((u16*)Cv)[(size_t)mm * N + nn] = f32_to_bf16(v);
      }
}

// ---------------- NT GEMM body, 128x128 tile (R18-verified, for gemm3) ------
// 16 MFMA per 8 ds_read_b128 per wave per kc-half -- 2x math/LDS-byte of
// BN=64. Needs ~135 VGPR: launch bounds (256,2) (cap at (256,4) spilled, R11).
__device__ __forceinline__ void gemm_body128(const u16* __restrict__ A,
                                             const u16* __restrict__ B,
                                             u16* __restrict__ C, int N, int K,
                                             float alpha, int bx, int by,
                                             u16* lA, u16* lB) {
  const int tid = threadIdx.x;
  const int lane = tid & 63;
  const int w = tid >> 6;
  const int c = lane & 15, g = lane >> 4;
  const int wm = (w & 1) * 64, wn = (w >> 1) * 64;
  const int m0 = by * 128, n0 = bx * 128;
  const int sr = tid >> 3, sc = tid & 7;

  f32x4 acc[4][4] = {};

  for (int k0 = 0; k0 < K; k0 += 64) {
    __syncthreads();
#pragma unroll
    for (int p = 0; p < 4; ++p) {
      int row = p * 32 + sr;
      int gc = sc ^ (row & 7);
      ld_lds16(A + (size_t)(m0 + row) * K + k0 + gc * 8, &lA[row * 64 + sc * 8]);
    }
#pragma unroll
    for (int p = 0; p < 4; ++p) {
      int row = p * 32 + sr;
      int gc = sc ^ (row & 7);
      ld_lds16(B + (size_t)(n0 + row) * K + k0 + gc * 8, &lB[row * 64 + sc * 8]);
    }
    __syncthreads();
#pragma unroll
    for (int kc = 0; kc < 2; ++kc) {
      bf16x8 a[4], b[4];
#pragma unroll
      for (int t = 0; t < 4; ++t) {
        int row = wm + t * 16 + c;
        int ch = (g + 4 * kc) ^ (row & 7);
        a[t] = *(const bf16x8*)&lA[row * 64 + ch * 8];
      }
#pragma unroll
      for (int t = 0; t < 4; ++t) {
        int row = wn + t * 16 + c;
        int ch = (g + 4 * kc) ^ (row & 7);
        b[t] = *(const bf16x8*)&lB[row * 64 + ch * 8];
      }
#pragma unroll
      for (int i = 0; i < 4; ++i)
#pragma unroll
        for (int j = 0; j < 4; ++j)
          acc[i][j] = MFMA16(a[i], b[j], acc[i][j]);
    }
  }

#pragma unroll
  for (int i = 0; i < 4; ++i)
#pragma unroll
    for (int j = 0; j < 4; ++j)
#pragma unroll
      for (int r = 0; r < 4; ++r) {
        int mm = m0 + wm + i * 16 + g * 4 + r;
        int nn = n0 + wn + j * 16 + c;
        C[(size_t)mm * N + nn] = f32_to_bf16(acc[i][j][r] * alpha);
      }
}

// fused launch: 3 input GEMMs, 128x128 tiles, grid 768 = 3 blocks/CU (R18)
__global__ __launch_bounds__(256, 2)
void gemm3(const u16* __restrict__ xq_b, const u16* __restrict__ wq_b,
           u16* __restrict__ Qb, const u16* __restrict__ xkv_b,
           const u16* __restrict__ wk_b, u16* __restrict__ Kb,
           const u16* __restrict__ wv_b, u16* __restrict__ VTb, float qscale) {
  __shared__ u16 lA[128 * 64];
  __shared__ u16 lB[128 * 64];
  int b = blockIdx.x;
  if (b < 256) {
    gemm_body128(xq_b, wq_b, Qb, 2048, 2048, qscale, b & 15, b >> 4, lA, lB);
  } else if (b < 512) {
    b -= 256;
    gemm_body128(xkv_b, wk_b, Kb, 512, 2048, 1.0f, b & 3, b >> 2, lA, lB);
  } else {
    b -= 512;
    gemm_body128(wv_b, xkv_b, VTb, 8192, 2048, 1.0f, b & 63, b >> 6, lA, lB);
  }
}

// single NT GEMM (final output, f32), BN=64 R9 config (grid 32x16 = 2/CU)
__global__ __launch_bounds__(256, 4)
void gemm_out(const u16* __restrict__ A, const u16* __restrict__ B,
              float* __restrict__ Cv) {
  __shared__ u16 lA[128 * 64];
  __shared__ u16 lB[64 * 64];
  gemm_body(A, B, Cv, 2048, 2048, 2048, 1.0f, blockIdx.x, blockIdx.y, 1, lA, lB);
}

// ---------------- fused flash attention v13 (R13/R15/R17/R18-verified) ------
// 32x32 MFMA, in-register P (cvt_pk + permlane32_swap), no-max softmax
// (shift-invariance), row-sums l on the MFMA pipe (ones-B MFMA), K/V LDS
// double-buffer with counted vmcnt(8), branch-free main loop + masked tail,
// phases interleaved so exp/pack(s0) overlaps QK(s1), exp/pack(s1) overlaps
// PV(s0). grid 512 = 2 kvs x 16 qb x 16 h; 4 waves x 32 q-rows; 2 blocks/CU.
// NOTE (R4/R6/R10/R11/R14/R16/R19): occupancy raises, tile shrinks, direct-V,
// and QK chain splits all measured and regress; this is the converged config.
__global__ __launch_bounds__(256, 2)
void attn_kernel(const u16* __restrict__ Q, const u16* __restrict__ Kg,
                 const u16* __restrict__ VT, float* __restrict__ Opart,
                 float* __restrict__ mlp) {
  __shared__ u16 lK[2][64 * 128];  // [j][d], chunk^=(j&15) swizzle
  __shared__ u16 lV[2][128 * 64];  // [d][j], chunk^=(d&7) swizzle

  const int tid = threadIdx.x;
  const int w = tid >> 6, lane = tid & 63;
  const int ql = lane & 31, hi = lane >> 5;
  const int bx = blockIdx.x;
  const int h = bx & 15, kvs = bx >> 8;
  const int qbr = (bx >> 4) & 15;
  const int qb = kvs ? qbr : 15 - qbr;  // load-balance remap (R7)
  const int hk = h >> 2;  // GQA
  const int i0 = qb * 128;
  const int q0 = i0 + w * 32;  // wave's 32 q-rows

  const int nt = ((i0 + 6271) >> 6) + 1;
  const int nth = nt >> 1;
  const int t0 = kvs ? nth : 0;
  const int ntt = (kvs ? nt : nth) - t0;
  // tiles with t_abs <= tsafe need no mask for any lane of this block
  const int tsafe = (i0 + 6081) >> 6;
  int nmain = tsafe + 1 - t0;
  if (nmain > ntt) nmain = ntt;
  if (nmain < 0) nmain = 0;

  // Q B-frag (32x32x16): lane holds Q[q0+ql][d = kc*16 + hi*8 .. +7]
  bf16x8 qf[8];
#pragma unroll
  for (int kc = 0; kc < 8; ++kc)
    qf[kc] = *(const bf16x8*)&Q[(size_t)(q0 + ql) * 2048 + h * 128 + kc * 16 + hi * 8];

  // ones B-frag for row-sum MFMA (l = P * 1)
  bf16x8 onesB;
#pragma unroll
  for (int i = 0; i < 8; ++i) onesB[i] = (short)0x3F80;

  f32x16 a[4] = {};   // O[q][d]: C-frag row q=(r&3)+8(r>>2)+4hi, col d=dt*32+ql
  f32x16 lacc = {};   // l[q] in C-frag rows (all cols identical)

  auto stage = [&](int buf, int t) {
    const int j0 = t << 6;
#pragma unroll
    for (int p = 0; p < 4; ++p) {
      int idx = p * 256 + tid;
      int row = idx >> 4, cc = idx & 15;
      int gc = cc ^ (row & 15);
      ld_lds16(Kg + (size_t)(j0 + row) * 512 + hk * 128 + gc * 8,
               &lK[buf][row * 128 + cc * 8]);
    }
#pragma unroll
    for (int p = 0; p < 4; ++p) {
      int idx = p * 256 + tid;
      int row = idx >> 3, cc = idx & 7;
      int gc = cc ^ (row & 7);
      ld_lds16(VT + (size_t)(hk * 128 + row) * 8192 + j0 + gc * 8,
               &lV[buf][row * 64 + cc * 8]);
    }
  };

  // finish one S half: exp2 in place, pack to two PV A-frags
  auto finish = [&](f32x16& sv, bf16x8& pA, bf16x8& pB) {
#pragma unroll
    for (int r = 0; r < 16; ++r) sv[r] = __builtin_amdgcn_exp2f(sv[r]);
    uint32_t A0 = cvt_pk_bf16(sv[0], sv[1]);
    uint32_t B0 = cvt_pk_bf16(sv[4], sv[5]);
    perm_swap(A0, B0);
    uint32_t A1 = cvt_pk_bf16(sv[2], sv[3]);
    uint32_t B1 = cvt_pk_bf16(sv[6], sv[7]);
    perm_swap(A1, B1);
    uint32_t A2 = cvt_pk_bf16(sv[8], sv[9]);
    uint32_t B2 = cvt_pk_bf16(sv[12], sv[13]);
    perm_swap(A2, B2);
    uint32_t A3 = cvt_pk_bf16(sv[10], sv[11]);
    uint32_t B3 = cvt_pk_bf16(sv[14], sv[15]);
    perm_swap(A3, B3);
    union { uint32_t u[4]; bf16x8 v; } pa, pb;
    pa.u[0] = A0; pa.u[1] = A1; pa.u[2] = B0; pa.u[3] = B1;
    pb.u[0] = A2; pb.u[1] = A3; pb.u[2] = B2; pb.u[3] = B3;
    pA = pa.v;
    pB = pb.v;
  };

  stage(0, t0);

  int it = 0;
  auto run_tiles = [&](int end, bool domask) {
    for (; it < end; ++it) {
      const int curb = it & 1;
      const int j0 = (t0 + it) << 6;
      if (it + 1 < ntt) {
        stage(curb ^ 1, t0 + it + 1);
        asm volatile("s_waitcnt vmcnt(8)" ::: "memory");
      } else {
        asm volatile("s_waitcnt vmcnt(0)" ::: "memory");
      }
      __builtin_amdgcn_s_barrier();

      f32x16 s0 = {}, s1 = {};
      bf16x8 pbf[4];
      // phase 1: QK s0 (pure MFMA cluster)
      __builtin_amdgcn_s_setprio(1);
#pragma unroll
      for (int kc = 0; kc < 8; ++kc) {
        int ch = kc * 2 + hi;
        bf16x8 kfa = *(const bf16x8*)&lK[curb][ql * 128 + (ch ^ (ql & 15)) * 8];
        s0 = MFMA32(kfa, qf[kc], s0);
      }
      __builtin_amdgcn_s_setprio(0);
      // phase 2: QK s1 (MFMA) || mask+exp+pack s0 (VALU)
#pragma unroll
      for (int kc = 0; kc < 8; ++kc) {
        int ch = kc * 2 + hi;
        bf16x8 kfb = *(const bf16x8*)&lK[curb][(32 + ql) * 128 + (ch ^ (ql & 15)) * 8];
        s1 = MFMA32(kfb, qf[kc], s1);
      }
      if (domask) {
#pragma unroll
        for (int r = 0; r < 16; ++r) {
          int jrow = (r & 3) + 8 * (r >> 2) + 4 * hi;
          if (j0 + jrow > q0 + ql + 6144) s0[r] = -1e30f;
        }
      }
      finish(s0, pbf[0], pbf[1]);
      // phase 3: PV s0 + ones (MFMA) || mask+exp+pack s1 (VALU)
      lacc = MFMA32(pbf[0], onesB, lacc);
      lacc = MFMA32(pbf[1], onesB, lacc);
#pragma unroll
      for (int kc = 0; kc < 2; ++kc)
#pragma unroll
        for (int dt = 0; dt < 4; ++dt) {
          int row = dt * 32 + ql;
          int ch = (kc * 2 + hi) ^ (row & 7);
          bf16x8 vf = *(const bf16x8*)&lV[curb][row * 64 + ch * 8];
          a[dt] = MFMA32(pbf[kc], vf, a[dt]);
        }
      if (domask) {
#pragma unroll
        for (int r = 0; r < 16; ++r) {
          int jrow = (r & 3) + 8 * (r >> 2) + 4 * hi;
          if (j0 + 32 + jrow > q0 + ql + 6144) s1[r] = -1e30f;
        }
      }
      finish(s1, pbf[2], pbf[3]);
      // phase 4: PV s1 + ones (pure MFMA cluster)
      __builtin_amdgcn_s_setprio(1);
      lacc = MFMA32(pbf[2], onesB, lacc);
      lacc = MFMA32(pbf[3], onesB, lacc);
#pragma unroll
      for (int kc = 2; kc < 4; ++kc)
#pragma unroll
        for (int dt = 0; dt < 4; ++dt) {
          int row = dt * 32 + ql;
          int ch = (kc * 2 + hi) ^ (row & 7);
          bf16x8 vf = *(const bf16x8*)&lV[curb][row * 64 + ch * 8];
          a[dt] = MFMA32(pbf[kc], vf, a[dt]);
        }
      __builtin_amdgcn_s_setprio(0);

      __builtin_amdgcn_s_barrier();
    }
  };

  run_tiles(nmain, false);  // hot loop: branch-free
  run_tiles(ntt, true);     // tail (<=3 tiles): exact per-lane mask

  // epilogue: store unnormalized partials (f32, [q][d] layout) + l
  const size_t pbase = ((size_t)(kvs * 16 + h) * 16 + qb);
  float* Op = Opart + pbase * 16384;
  float* mlb = mlp + pbase * 256;
#pragma unroll
  for (int dt = 0; dt < 4; ++dt)
#pragma unroll
    for (int r = 0; r < 16; ++r) {
      int qrow = w * 32 + (r & 3) + 8 * (r >> 2) + 4 * hi;
      Op[(size_t)qrow * 128 + dt * 32 + ql] = a[dt][r];
    }
  if (ql == 0) {  // lanes 0 and 32: disjoint q-row sets via hi
#pragma unroll
    for (int r = 0; r < 16; ++r)
      mlb[128 + w * 32 + (r & 3) + 8 * (r >> 2) + 4 * hi] = lacc[r];
  }
}

// ---------------- merge the two KV-half partials (no max: weights = 1) ------
__global__ __launch_bounds__(256)
void attn_merge(const float* __restrict__ Opart, const float* __restrict__ mlp,
                u16* __restrict__ O) {
  const int bx = blockIdx.x;  // h*16 + qb
  const int h = bx >> 4, qb = bx & 15;
  const int q = threadIdx.x & 127, hf = threadIdx.x >> 7;
  const size_t p0 = ((size_t)(0 + h) * 16 + qb);
  const size_t p1 = ((size_t)(16 + h) * 16 + qb);
  float ll0 = mlp[p0 * 256 + 128 + q], ll1 = mlp[p1 * 256 + 128 + q];
  float inv = 1.f / (ll0 + ll1);
  const float* A = Opart + p0 * 16384 + (size_t)q * 128 + hf * 64;
  const float* B = Opart + p1 * 16384 + (size_t)q * 128 + hf * 64;
  u16* out = O + (size_t)(qb * 128 + q) * 2048 + h * 128 + hf * 64;
#pragma unroll
  for (int d = 0; d < 64; d += 4) {
    float4 a = *(const float4*)&A[d];
    float4 b = *(const float4*)&B[d];
    ushort4 o;
    o.x = f32_to_bf16((a.x + b.x) * inv);
    o.y = f32_to_bf16((a.y + b.y) * inv);
    o.z = f32_to_bf16((a.z + b.z) * inv);
    o.w = f32_to_bf16((a.w + b.w) * inv);
    *(ushort4*)&out[d] = o;
  }
}

// ---------------- launch ----------------
extern "C" void kernel_launch(void* const* d_in, const int* in_sizes, int n_in,
                              void* d_out, int out_size, void* d_ws, size_t ws_size,
                              hipStream_t stream) {
  (void)in_sizes; (void)n_in; (void)out_size; (void)ws_size;
  const float* xq = (const float*)d_in[0];   // [2048][2048]
  const float* xkv = (const float*)d_in[1];  // [8192][2048]
  const float* Wq = (const float*)d_in[2];   // [2048][2048]
  const float* Wk = (const float*)d_in[3];   // [512][2048]
  const float* Wv = (const float*)d_in[4];   // [512][2048]
  const float* Wo = (const float*)d_in[5];   // [2048][2048]

  u16* ws = (u16*)d_ws;
  const size_t M1 = 1024 * 1024;
  u16* xq_b  = ws;             // dead after gemm3
  u16* xkv_b = ws + 4 * M1;    // dead after gemm3
  u16* wq_b  = ws + 20 * M1;
  u16* wk_b  = ws + 24 * M1;
  u16* wv_b  = ws + 25 * M1;
  u16* wo_b  = ws + 26 * M1;   // LIVE until gemm_out
  u16* Qb    = ws + 30 * M1;   // pre-scaled by log2e/sqrt(D)
  u16* Kb    = ws + 34 * M1;   // [8192][512]
  u16* VTb   = ws + 38 * M1;   // [512][8192]
  u16* Ob    = ws + 42 * M1;
  // attn partials alias the dead xq_b/xkv_b region (34.1MB <= 40MB)
  float* Opart = (float*)d_ws;            // 2*16*16*128*128 f32
  float* mlptr = Opart + 8388608;         // 2*16*16*256 f32

  cvt_all<<<2048, 256, 0, stream>>>(xq, xkv, Wq, Wk, Wv, Wo,
                                    xq_b, xkv_b, wq_b, wk_b, wv_b, wo_b);

  // Q = x_q Wq^T (scaled); K = x_kv Wk^T; V^T = Wv x_kv^T -- one fused launch
  gemm3<<<768, 256, 0, stream>>>(xq_b, wq_b, Qb, xkv_b, wk_b, Kb, wv_b, VTb,
                                 0.12752837f);

  attn_kernel<<<512, 256, 0, stream>>>(Qb, Kb, VTb, Opart, mlptr);
  attn_merge<<<256, 256, 0, stream>>>(Opart, mlptr, Ob);

  // out = O Wo^T (f32 output)
  gemm_out<<<dim3(32, 16), 256, 0, stream>>>(Ob, wo_b, (float*)d_out);
}